// Round 1
// baseline (8470.143 us; speedup 1.0000x reference)
//
#include <hip/hip_runtime.h>
#include <hip/hip_bf16.h>

#define NRAYS 2048
#define NSAMP 128
#define NS_TOT (NRAYS*NSAMP)

__device__ __forceinline__ float sigmoidf(float x){ return 1.f/(1.f+expf(-x)); }

__device__ __forceinline__ float approx_cdf_f(float x){
  return 0.5f*(1.f + tanhf(0.7978845608028654f*(x + 0.044715f*x*x*x)));
}

// Giles (2010) single-precision erfinv, max rel err ~1e-6
__device__ __forceinline__ float erfinvf_dev(float x){
  float w = -logf((1.0f-x)*(1.0f+x));
  float p;
  if (w < 5.0f){
    w -= 2.5f;
    p = 2.81022636e-08f;
    p = fmaf(p,w, 3.43273939e-07f);
    p = fmaf(p,w,-3.5233877e-06f);
    p = fmaf(p,w,-4.39150654e-06f);
    p = fmaf(p,w, 0.00021858087f);
    p = fmaf(p,w,-0.00125372503f);
    p = fmaf(p,w,-0.00417768164f);
    p = fmaf(p,w, 0.246640727f);
    p = fmaf(p,w, 1.50140941f);
  } else {
    w = sqrtf(w) - 3.0f;
    p = -0.000200214257f;
    p = fmaf(p,w, 0.000100950558f);
    p = fmaf(p,w, 0.00134934322f);
    p = fmaf(p,w,-0.00367342844f);
    p = fmaf(p,w, 0.00573950773f);
    p = fmaf(p,w,-0.0076224613f);
    p = fmaf(p,w, 0.00943887047f);
    p = fmaf(p,w, 1.00167406f);
    p = fmaf(p,w, 2.83297682f);
  }
  return p*x;
}

// ---------- per-ray setup: viewdirs -> direnc[27] ----------
__global__ void k_setup(const float* __restrict__ rd, float* __restrict__ direnc){
  int r = blockIdx.x*blockDim.x + threadIdx.x;
  if (r >= NRAYS) return;
  float x = rd[r*3], y = rd[r*3+1], z = rd[r*3+2];
  float n = sqrtf(x*x+y*y+z*z);
  float v[3] = {x/n, y/n, z/n};
  float* o = direnc + (size_t)r*27;
  o[0]=v[0]; o[1]=v[1]; o[2]=v[2];
  #pragma unroll
  for (int f=0; f<4; f++){
    float sc = (float)(1<<f);
    #pragma unroll
    for (int j=0;j<3;j++){
      float a = v[j]*sc;
      o[3  + f*3 + j] = sinf(a);
      o[15 + f*3 + j] = cosf(a);
    }
  }
}

// ---------- per-ray dir contribution to Wd layer: dctr[r][j] = bd[j] + direnc[r]·Wd[256:283, j] ----------
__global__ void k_dctr(const float* __restrict__ direnc, const float* __restrict__ Wd,
                       const float* __restrict__ bd, float* __restrict__ dctr){
  int g = blockIdx.x*blockDim.x + threadIdx.x;
  if (g >= NRAYS*128) return;
  int r = g >> 7, j = g & 127;
  float acc = bd[j];
  const float* de = direnc + (size_t)r*27;
  #pragma unroll
  for (int k=0;k<27;k++) acc = fmaf(de[k], Wd[(size_t)(256+k)*128 + j], acc);
  dctr[g] = acc;
}

// ---------- cast_rays + integrated_pos_enc ----------
__global__ void k_enc(const float* __restrict__ ro, const float* __restrict__ rd,
                      const float* __restrict__ rr, const float* __restrict__ tfine,
                      float* __restrict__ enc, int rayBase, int Mc){
  int t = blockIdx.x*blockDim.x + threadIdx.x;
  if (t >= Mc) return;
  int ray = rayBase + (t>>7);
  int s = t & 127;
  float t0, t1;
  if (tfine){ t0 = tfine[(size_t)ray*129+s]; t1 = tfine[(size_t)ray*129+s+1]; }
  else      { t0 = 2.f + 4.f*(float)s/128.f; t1 = 2.f + 4.f*(float)(s+1)/128.f; }
  float c = 0.5f*(t0+t1), d = 0.5f*(t1-t0);
  float c2 = c*c, d2 = d*d;
  float denom = 3.f*c2 + d2;
  float t_mean = c + 2.f*c*d2/denom;
  float d4 = d2*d2;
  float t_var = d2*(1.f/3.f) - (4.f/15.f)*(d4*(12.f*c2 - d2))/(denom*denom);
  float rrv = rr[ray];
  float r_var = rrv*rrv*(c2*0.25f + (5.f/12.f)*d2 - (4.f/15.f)*d4/denom);
  float rdv[3] = {rd[ray*3], rd[ray*3+1], rd[ray*3+2]};
  float rov[3] = {ro[ray*3], ro[ray*3+1], ro[ray*3+2]};
  float dd = rdv[0]*rdv[0]+rdv[1]*rdv[1]+rdv[2]*rdv[2];
  float invdd = 1.f/fmaxf(dd, 1e-10f);
  float* e = enc + (size_t)t*96;
  #pragma unroll
  for (int j=0;j<3;j++){
    float mean = rov[j] + rdv[j]*t_mean;
    float doj = rdv[j]*rdv[j];
    float cov = t_var*doj + r_var*(1.f - doj*invdd);
    float sc = 1.f;
    for (int k=0;k<16;k++){
      float att = expf(-0.5f*cov*sc*sc);
      float sv, cv;
      sincosf(mean*sc, &sv, &cv);
      e[k*3+j]      = sv*att;
      e[48+k*3+j]   = cv*att;
      sc *= 2.f;
    }
  }
}

// ---------- fp32 GEMM: C = act(A[M,K] @ B[K,N] + bias[col] + rowadd[row/128, col]) ----------
#define BM 128
#define BN 128
#define BK 8
__global__ __launch_bounds__(256) void k_gemm(
    const float* __restrict__ A, const float* __restrict__ B,
    const float* __restrict__ bias, const float* __restrict__ rowadd,
    float* __restrict__ C, int M, int N, int K, int relu)
{
  __shared__ float As[BK][BM+4];
  __shared__ float Bs[BK][BN+4];
  int tid = threadIdx.x;
  int bm = blockIdx.x * BM;
  int bn = blockIdx.y * BN;
  int tx = tid & 15, ty = tid >> 4;
  float acc[8][8] = {};
  for (int kk = 0; kk < K; kk += BK) {
    #pragma unroll
    for (int i=0;i<4;i++){
      int l = tid*4+i; int m = l>>3; int k = l&7;
      float v = 0.f;
      if (kk+k < K) v = A[(size_t)(bm+m)*K + kk + k];
      As[k][m] = v;
    }
    #pragma unroll
    for (int i=0;i<4;i++){
      int l = tid*4+i; int k = l>>7; int n = l&127;
      float v = 0.f;
      if (kk+k < K) v = B[(size_t)(kk+k)*N + bn + n];
      Bs[k][n] = v;
    }
    __syncthreads();
    #pragma unroll
    for (int k=0;k<BK;k++){
      float a[8], b[8];
      #pragma unroll
      for (int i=0;i<8;i++) a[i] = As[k][ty*8+i];
      #pragma unroll
      for (int j=0;j<8;j++) b[j] = Bs[k][tx*8+j];
      #pragma unroll
      for (int i=0;i<8;i++)
        #pragma unroll
        for (int j=0;j<8;j++)
          acc[i][j] = fmaf(a[i], b[j], acc[i][j]);
    }
    __syncthreads();
  }
  #pragma unroll
  for (int i=0;i<8;i++){
    int r = bm + ty*8 + i;
    #pragma unroll
    for (int j=0;j<8;j++){
      int c = bn + tx*8 + j;
      float v = acc[i][j];
      if (bias)   v += bias[c];
      if (rowadd) v += rowadd[(size_t)(r>>7)*N + c];
      if (relu)   v = fmaxf(v, 0.f);
      C[(size_t)r*N + c] = v;
    }
  }
}

// ---------- narrow heads from X[M,256]: sigma (+ mus,sigs if Wm) ----------
__global__ void k_headsA(const float* __restrict__ X, const float* __restrict__ Ws,
                         const float* __restrict__ bs, const float* __restrict__ Wm,
                         const float* __restrict__ bm, float* __restrict__ sigma,
                         float* __restrict__ mus, float* __restrict__ sigs,
                         int M, size_t gbase){
  int wid = (blockIdx.x*blockDim.x + threadIdx.x) >> 6;
  int lane = threadIdx.x & 63;
  if (wid >= M) return;
  const float* x = X + (size_t)wid*256;
  float s0=0.f,s1=0.f,s2=0.f;
  for (int k=lane;k<256;k+=64){
    float xv = x[k];
    s0 = fmaf(xv, Ws[k], s0);
    if (Wm){ s1 = fmaf(xv, Wm[2*k], s1); s2 = fmaf(xv, Wm[2*k+1], s2); }
  }
  #pragma unroll
  for (int off=32; off>0; off>>=1){
    s0 += __shfl_down(s0, off);
    s1 += __shfl_down(s1, off);
    s2 += __shfl_down(s2, off);
  }
  if (lane==0){
    sigma[gbase+wid] = s0 + bs[0];
    if (Wm){ mus[gbase+wid] = s1 + bm[0]; sigs[gbase+wid] = s2 + bm[1]; }
  }
}

// ---------- rgb head from h[M,128] ----------
__global__ void k_headsB(const float* __restrict__ H, const float* __restrict__ Wr,
                         const float* __restrict__ br, float* __restrict__ rgbs,
                         int M, size_t gbase){
  int wid = (blockIdx.x*blockDim.x + threadIdx.x) >> 6;
  int lane = threadIdx.x & 63;
  if (wid >= M) return;
  const float* h = H + (size_t)wid*128;
  float s0=0.f,s1=0.f,s2=0.f;
  for (int k=lane;k<128;k+=64){
    float hv = h[k];
    s0 = fmaf(hv, Wr[3*k  ], s0);
    s1 = fmaf(hv, Wr[3*k+1], s1);
    s2 = fmaf(hv, Wr[3*k+2], s2);
  }
  #pragma unroll
  for (int off=32; off>0; off>>=1){
    s0 += __shfl_down(s0, off);
    s1 += __shfl_down(s1, off);
    s2 += __shfl_down(s2, off);
  }
  if (lane==0){
    rgbs[(gbase+wid)*3  ] = s0 + br[0];
    rgbs[(gbase+wid)*3+1] = s1 + br[1];
    rgbs[(gbase+wid)*3+2] = s2 + br[2];
  }
}

// ---------- coarse volume render + inverse-CDF fine sampling (one block per ray) ----------
__global__ __launch_bounds__(256) void k_vr_coarse(
    const float* __restrict__ sigmaC, const float* __restrict__ rgbsC,
    const float* __restrict__ musRaw, const float* __restrict__ sigsRaw,
    const float* __restrict__ rd, float* __restrict__ out_rgbc,
    float* __restrict__ tfine){
  int ray = blockIdx.x, tid = threadIdx.x;
  __shared__ float sh_w[128], sh_pdf[128], sh_cdf[129], sh_lt[128], sh_pib[128], sh_mu[128], sh_sg[128];
  __shared__ float red[256];
  __shared__ float s_wsum;
  float rx = rd[ray*3], ry = rd[ray*3+1], rz = rd[ray*3+2];
  float rn = sqrtf(rx*rx+ry*ry+rz*rz);
  if (tid < 128){
    float sg = fmaxf(sigmaC[(size_t)ray*128+tid], 0.f);
    float alpha = 1.f - expf(-sg * (0.03125f*rn));
    sh_w[tid] = alpha;
    float mu = sigmoidf(musRaw[(size_t)ray*128+tid]);
    float sig = sigmoidf(sigsRaw[(size_t)ray*128+tid]) + 0.001f;
    float sm = 2.f*sig;
    sh_mu[tid]=mu; sh_sg[tid]=sm;
    float lt = approx_cdf_f((0.f-mu)/sm);
    sh_lt[tid]=lt;
    sh_pib[tid]=approx_cdf_f((1.f-mu)/sm) - lt;
  }
  __syncthreads();
  if (tid == 0){
    float T = 1.f;
    for (int s=0;s<128;s++){ float a=sh_w[s]; sh_w[s]=a*T; T *= (1.f-a+1e-10f); }
  }
  __syncthreads();
  for (int ch=0; ch<3; ch++){
    float v = 0.f;
    if (tid<128) v = sh_w[tid]*sigmoidf(rgbsC[((size_t)ray*128+tid)*3+ch]);
    red[tid]=v; __syncthreads();
    for (int o=128;o>0;o>>=1){ if (tid<o) red[tid]+=red[tid+o]; __syncthreads(); }
    if (tid==0) out_rgbc[ray*3+ch] = red[0];
    __syncthreads();
  }
  { float v = (tid<128)? (sh_w[tid]+1e-5f) : 0.f;
    red[tid]=v; __syncthreads();
    for (int o=128;o>0;o>>=1){ if (tid<o) red[tid]+=red[tid+o]; __syncthreads(); }
    if (tid==0) s_wsum = red[0];
    __syncthreads(); }
  if (tid<128) sh_pdf[tid] = (sh_w[tid]+1e-5f)/s_wsum;
  __syncthreads();
  if (tid==0){
    float c=0.f; sh_cdf[0]=0.f;
    for (int s=0;s<128;s++){ c += sh_pdf[s]; sh_cdf[s+1]=c; }
  }
  __syncthreads();
  if (tid < 129){
    float u = (float)tid * ((1.f-1e-5f)/128.f);
    int lo=0, hi=129;
    while (lo<hi){ int mid=(lo+hi)>>1; if (sh_cdf[mid] <= u) lo=mid+1; else hi=mid; }
    int idx = lo-1; idx = idx<0?0:(idx>127?127:idx);
    float frac = (u - sh_cdf[idx]) / fmaxf(sh_pdf[idx], 1e-10f);
    frac = fminf(fmaxf(frac,0.f),1.f);
    float p = sh_lt[idx] + frac*sh_pib[idx];
    p = fminf(fmaxf(p, 1e-5f), 1.f-1e-5f);
    float xx = sh_mu[idx] + sh_sg[idx]*1.4142135623730951f*erfinvf_dev(2.f*p-1.f);
    xx = fminf(fmaxf(xx,0.f),1.f);
    float b0 = 2.f + 0.03125f*(float)idx;
    tfine[(size_t)ray*129+tid] = b0 + xx*0.03125f;
  }
}

// ---------- fine volume render: rgb_f, depth_f, acc_f ----------
__global__ __launch_bounds__(256) void k_vr_fine(
    const float* __restrict__ sigmaF, const float* __restrict__ rgbsF,
    const float* __restrict__ tfine, const float* __restrict__ rd,
    float* __restrict__ dout){
  int ray=blockIdx.x, tid=threadIdx.x;
  __shared__ float sh_w[128], sh_tm[128];
  __shared__ float red[256];
  float rx=rd[ray*3], ry=rd[ray*3+1], rz=rd[ray*3+2];
  float rn = sqrtf(rx*rx+ry*ry+rz*rz);
  if (tid<128){
    float t0=tfine[(size_t)ray*129+tid], t1=tfine[(size_t)ray*129+tid+1];
    float sg=fmaxf(sigmaF[(size_t)ray*128+tid],0.f);
    float alpha = 1.f-expf(-sg*(t1-t0)*rn);
    sh_w[tid]=alpha;
    sh_tm[tid]=0.5f*(t0+t1);
  }
  __syncthreads();
  if (tid==0){ float T=1.f; for(int s=0;s<128;s++){ float a=sh_w[s]; sh_w[s]=a*T; T*=(1.f-a+1e-10f);} }
  __syncthreads();
  for (int ch=0; ch<3; ch++){
    float v=0.f;
    if (tid<128) v = sh_w[tid]*sigmoidf(rgbsF[((size_t)ray*128+tid)*3+ch]);
    red[tid]=v; __syncthreads();
    for(int o=128;o>0;o>>=1){ if(tid<o) red[tid]+=red[tid+o]; __syncthreads(); }
    if (tid==0) dout[NRAYS*3 + ray*3 + ch] = red[0];
    __syncthreads();
  }
  { float v = (tid<128)? sh_w[tid]*sh_tm[tid] : 0.f;
    red[tid]=v; __syncthreads();
    for(int o=128;o>0;o>>=1){ if(tid<o) red[tid]+=red[tid+o]; __syncthreads(); }
    if (tid==0) dout[NRAYS*6 + ray] = red[0];
    __syncthreads(); }
  { float v = (tid<128)? sh_w[tid] : 0.f;
    red[tid]=v; __syncthreads();
    for(int o=128;o>0;o>>=1){ if(tid<o) red[tid]+=red[tid+o]; __syncthreads(); }
    if (tid==0) dout[NRAYS*7 + ray] = red[0]; }
}

extern "C" void kernel_launch(void* const* d_in, const int* in_sizes, int n_in,
                              void* d_out, int out_size, void* d_ws, size_t ws_size,
                              hipStream_t stream) {
  const float* ro  = (const float*)d_in[0];
  const float* rd  = (const float*)d_in[1];
  const float* rr  = (const float*)d_in[2];
  const float* cW0 = (const float*)d_in[3];  const float* cb0 = (const float*)d_in[4];
  const float* cWh = (const float*)d_in[5];  const float* cbh = (const float*)d_in[6];
  const float* cWs = (const float*)d_in[7];  const float* cbs = (const float*)d_in[8];
  const float* cWb = (const float*)d_in[9];  const float* cbb = (const float*)d_in[10];
  const float* cWd = (const float*)d_in[11]; const float* cbd = (const float*)d_in[12];
  const float* cWr = (const float*)d_in[13]; const float* cbr = (const float*)d_in[14];
  // setup_inputs() dict order: fine params at 15..26, cWm/cbm at 27/28.
  // Defensive: if index 15 holds 512 elements it's cWm (signature order) -> remap.
  int iWm = 27, ibm = 28, ifb = 15;
  if (n_in > 15 && in_sizes[15] == 512){ iWm = 15; ibm = 16; ifb = 17; }
  const float* fW0 = (const float*)d_in[ifb+0];  const float* fb0 = (const float*)d_in[ifb+1];
  const float* fWh = (const float*)d_in[ifb+2];  const float* fbh = (const float*)d_in[ifb+3];
  const float* fWs = (const float*)d_in[ifb+4];  const float* fbs = (const float*)d_in[ifb+5];
  const float* fWb = (const float*)d_in[ifb+6];  const float* fbb = (const float*)d_in[ifb+7];
  const float* fWd = (const float*)d_in[ifb+8];  const float* fbd = (const float*)d_in[ifb+9];
  const float* fWr = (const float*)d_in[ifb+10]; const float* fbr = (const float*)d_in[ifb+11];
  const float* cWm = (const float*)d_in[iWm];    const float* cbm = (const float*)d_in[ibm];

  float* ws = (float*)d_ws;
  size_t off = 0;
  auto alloc = [&](size_t n){ float* p = ws + off; off += n; return p; };
  float* direnc  = alloc((size_t)NRAYS*27);
  float* dctrC   = alloc((size_t)NRAYS*128);
  float* dctrF   = alloc((size_t)NRAYS*128);
  float* sigmaC  = alloc(NS_TOT);
  float* musRaw  = alloc(NS_TOT);
  float* sigsRaw = alloc(NS_TOT);
  float* rgbsC   = alloc((size_t)NS_TOT*3);
  float* tfine   = alloc((size_t)NRAYS*129);
  float* sigmaF  = alloc(NS_TOT);
  float* rgbsF   = alloc((size_t)NS_TOT*3);

  size_t totalF = ws_size/sizeof(float);
  size_t remain = (totalF > off) ? (totalF - off) : 0;
  const size_t perRay = 128*(96+256+256+128);
  int R = (int)(remain / perRay);
  if (R > NRAYS) R = NRAYS;
  if (R < 1) R = 1;
  float* encB = ws + off;
  float* ping = encB + (size_t)R*128*96;
  float* pong = ping + (size_t)R*128*256;
  float* hbuf = pong + (size_t)R*128*256;

  k_setup<<<(NRAYS+255)/256, 256, 0, stream>>>(rd, direnc);
  k_dctr<<<(NRAYS*128)/256, 256, 0, stream>>>(direnc, cWd, cbd, dctrC);
  k_dctr<<<(NRAYS*128)/256, 256, 0, stream>>>(direnc, fWd, fbd, dctrF);

  // ---- coarse MLP ----
  for (int base=0; base<NRAYS; base+=R){
    int rays = (NRAYS-base < R) ? (NRAYS-base) : R;
    int Mc = rays*128;
    dim3 g2(Mc/128, 2), g1(Mc/128, 1);
    k_enc<<<(Mc+255)/256, 256, 0, stream>>>(ro, rd, rr, nullptr, encB, base, Mc);
    k_gemm<<<g2,256,0,stream>>>(encB, cW0, cb0, nullptr, ping, Mc,256, 96, 1);
    k_gemm<<<g2,256,0,stream>>>(ping, cWh,        cbh,     nullptr, pong, Mc,256,256, 1);
    k_gemm<<<g2,256,0,stream>>>(pong, cWh+65536,  cbh+256, nullptr, ping, Mc,256,256, 1);
    k_gemm<<<g2,256,0,stream>>>(ping, cWh+131072, cbh+512, nullptr, pong, Mc,256,256, 1);
    k_headsA<<<Mc/4,256,0,stream>>>(pong, cWs, cbs, cWm, cbm, sigmaC, musRaw, sigsRaw, Mc, (size_t)base*128);
    k_gemm<<<g2,256,0,stream>>>(pong, cWb, cbb, nullptr, ping, Mc,256,256, 0);
    k_gemm<<<g1,256,0,stream>>>(ping, cWd, nullptr, dctrC+(size_t)base*128, hbuf, Mc,128,256, 1);
    k_headsB<<<Mc/4,256,0,stream>>>(hbuf, cWr, cbr, rgbsC, Mc, (size_t)base*128);
  }
  k_vr_coarse<<<NRAYS,256,0,stream>>>(sigmaC, rgbsC, musRaw, sigsRaw, rd, (float*)d_out, tfine);

  // ---- fine MLP ----
  for (int base=0; base<NRAYS; base+=R){
    int rays = (NRAYS-base < R) ? (NRAYS-base) : R;
    int Mc = rays*128;
    dim3 g2(Mc/128, 2), g1(Mc/128, 1);
    k_enc<<<(Mc+255)/256, 256, 0, stream>>>(ro, rd, rr, tfine, encB, base, Mc);
    k_gemm<<<g2,256,0,stream>>>(encB, fW0, fb0, nullptr, ping, Mc,256, 96, 1);
    k_gemm<<<g2,256,0,stream>>>(ping, fWh,        fbh,     nullptr, pong, Mc,256,256, 1);
    k_gemm<<<g2,256,0,stream>>>(pong, fWh+65536,  fbh+256, nullptr, ping, Mc,256,256, 1);
    k_gemm<<<g2,256,0,stream>>>(ping, fWh+131072, fbh+512, nullptr, pong, Mc,256,256, 1);
    k_headsA<<<Mc/4,256,0,stream>>>(pong, fWs, fbs, nullptr, nullptr, sigmaF, nullptr, nullptr, Mc, (size_t)base*128);
    k_gemm<<<g2,256,0,stream>>>(pong, fWb, fbb, nullptr, ping, Mc,256,256, 0);
    k_gemm<<<g1,256,0,stream>>>(ping, fWd, nullptr, dctrF+(size_t)base*128, hbuf, Mc,128,256, 1);
    k_headsB<<<Mc/4,256,0,stream>>>(hbuf, fWr, fbr, rgbsF, Mc, (size_t)base*128);
  }
  k_vr_fine<<<NRAYS,256,0,stream>>>(sigmaF, rgbsF, tfine, rd, (float*)d_out);
}

// Round 4
// 3173.454 us; speedup vs baseline: 2.6691x; 2.6691x over previous
//
#include <hip/hip_runtime.h>
#include <hip/hip_bf16.h>

#define NRAYS 2048
#define NSAMP 128
#define NS_TOT (NRAYS*NSAMP)

typedef _Float16 f16;
typedef __attribute__((ext_vector_type(4))) _Float16 f16x4;
typedef __attribute__((ext_vector_type(8))) _Float16 f16x8;
typedef __attribute__((ext_vector_type(4))) float f32x4;

__device__ __forceinline__ float sigmoidf(float x){ return 1.f/(1.f+expf(-x)); }

__device__ __forceinline__ float approx_cdf_f(float x){
  return 0.5f*(1.f + tanhf(0.7978845608028654f*(x + 0.044715f*x*x*x)));
}

// Giles (2010) single-precision erfinv, max rel err ~1e-6
__device__ __forceinline__ float erfinvf_dev(float x){
  float w = -logf((1.0f-x)*(1.0f+x));
  float p;
  if (w < 5.0f){
    w -= 2.5f;
    p = 2.81022636e-08f;
    p = fmaf(p,w, 3.43273939e-07f);
    p = fmaf(p,w,-3.5233877e-06f);
    p = fmaf(p,w,-4.39150654e-06f);
    p = fmaf(p,w, 0.00021858087f);
    p = fmaf(p,w,-0.00125372503f);
    p = fmaf(p,w,-0.00417768164f);
    p = fmaf(p,w, 0.246640727f);
    p = fmaf(p,w, 1.50140941f);
  } else {
    w = sqrtf(w) - 3.0f;
    p = -0.000200214257f;
    p = fmaf(p,w, 0.000100950558f);
    p = fmaf(p,w, 0.00134934322f);
    p = fmaf(p,w,-0.00367342844f);
    p = fmaf(p,w, 0.00573950773f);
    p = fmaf(p,w,-0.0076224613f);
    p = fmaf(p,w, 0.00943887047f);
    p = fmaf(p,w, 1.00167406f);
    p = fmaf(p,w, 2.83297682f);
  }
  return p*x;
}

// ---------- weight convert+transpose+split: W[Ksrc][N] f32 -> Wh/Wl[N][Kdst] f16 ----------
__global__ void k_cvtT(const float* __restrict__ W, f16* __restrict__ Wh, f16* __restrict__ Wl,
                       int Ksrc, int N, int Kdst){
  int g = blockIdx.x*blockDim.x + threadIdx.x;
  if (g >= N*Kdst) return;
  int n = g / Kdst, k = g - n*Kdst;
  float v = (k < Ksrc) ? W[(size_t)k*N + n] : 0.f;
  f16 h = (f16)v;
  Wh[g] = h;
  Wl[g] = (f16)(v - (float)h);
}

// ---------- per-ray setup: viewdirs -> direnc[27] ----------
__global__ void k_setup(const float* __restrict__ rd, float* __restrict__ direnc){
  int r = blockIdx.x*blockDim.x + threadIdx.x;
  if (r >= NRAYS) return;
  float x = rd[r*3], y = rd[r*3+1], z = rd[r*3+2];
  float n = sqrtf(x*x+y*y+z*z);
  float v[3] = {x/n, y/n, z/n};
  float* o = direnc + (size_t)r*27;
  o[0]=v[0]; o[1]=v[1]; o[2]=v[2];
  #pragma unroll
  for (int f=0; f<4; f++){
    float sc = (float)(1<<f);
    #pragma unroll
    for (int j=0;j<3;j++){
      float a = v[j]*sc;
      o[3  + f*3 + j] = sinf(a);
      o[15 + f*3 + j] = cosf(a);
    }
  }
}

// ---------- per-ray dir contribution: dctr[r][j] = bd[j] + direnc[r]·Wd[256:283, j] ----------
__global__ void k_dctr(const float* __restrict__ direnc, const float* __restrict__ Wd,
                       const float* __restrict__ bd, float* __restrict__ dctr){
  int g = blockIdx.x*blockDim.x + threadIdx.x;
  if (g >= NRAYS*128) return;
  int r = g >> 7, j = g & 127;
  float acc = bd[j];
  const float* de = direnc + (size_t)r*27;
  #pragma unroll
  for (int k=0;k<27;k++) acc = fmaf(de[k], Wd[(size_t)(256+k)*128 + j], acc);
  dctr[g] = acc;
}

// ---------- cast_rays + integrated_pos_enc -> f32 enc[M][128] (cols 96..127 zero) ----------
__global__ void k_enc(const float* __restrict__ ro, const float* __restrict__ rd,
                      const float* __restrict__ rr, const float* __restrict__ tfine,
                      float* __restrict__ enc, int rayBase, int Mc){
  int t = blockIdx.x*blockDim.x + threadIdx.x;
  if (t >= Mc) return;
  int ray = rayBase + (t>>7);
  int s = t & 127;
  float t0, t1;
  if (tfine){ t0 = tfine[(size_t)ray*129+s]; t1 = tfine[(size_t)ray*129+s+1]; }
  else      { t0 = 2.f + 4.f*(float)s/128.f; t1 = 2.f + 4.f*(float)(s+1)/128.f; }
  float c = 0.5f*(t0+t1), d = 0.5f*(t1-t0);
  float c2 = c*c, d2 = d*d;
  float denom = 3.f*c2 + d2;
  float t_mean = c + 2.f*c*d2/denom;
  float d4 = d2*d2;
  float t_var = d2*(1.f/3.f) - (4.f/15.f)*(d4*(12.f*c2 - d2))/(denom*denom);
  float rrv = rr[ray];
  float r_var = rrv*rrv*(c2*0.25f + (5.f/12.f)*d2 - (4.f/15.f)*d4/denom);
  float rdv[3] = {rd[ray*3], rd[ray*3+1], rd[ray*3+2]};
  float rov[3] = {ro[ray*3], ro[ray*3+1], ro[ray*3+2]};
  float dd = rdv[0]*rdv[0]+rdv[1]*rdv[1]+rdv[2]*rdv[2];
  float invdd = 1.f/fmaxf(dd, 1e-10f);
  float* e = enc + (size_t)t*128;
  #pragma unroll
  for (int j=0;j<3;j++){
    float mean = rov[j] + rdv[j]*t_mean;
    float doj = rdv[j]*rdv[j];
    float cov = t_var*doj + r_var*(1.f - doj*invdd);
    float sc = 1.f;
    for (int k=0;k<16;k++){
      float att = expf(-0.5f*cov*sc*sc);
      float sv, cv;
      sincosf(mean*sc, &sv, &cv);
      e[k*3+j]      = sv*att;
      e[48+k*3+j]   = cv*att;
      sc *= 2.f;
    }
  }
  #pragma unroll
  for (int k=96;k<128;k++) e[k] = 0.f;
}

// ---------- split-fp16 MFMA GEMM (fp32-equivalent): C = act(A @ BT^T + bias + rowadd) ----------
// A fp32 [M][K]; B pre-split Wh/Wl f16 [N][K]; acc = Ah*Bh + Ah*Bl + Al*Bh (fp32 accumulate).
#define TM 128
#define TN 128
#define TK 64
#define LDP 72   // padded LDS leading dim (f16): 144B stride -> 2-way bank alias (free)
__global__ __launch_bounds__(256) void k_gemm_split(
    const float* __restrict__ A,      // [M][K] fp32
    const f16* __restrict__ BTh,      // [N][K]
    const f16* __restrict__ BTl,      // [N][K]
    const float* __restrict__ bias,   // [N] or null
    const float* __restrict__ rowadd, // [M/128][N] or null
    float* __restrict__ C,            // [M][N] fp32
    int M, int N, int K, int relu)
{
  __shared__ __align__(16) f16 Ahs[TM*LDP];
  __shared__ __align__(16) f16 Als[TM*LDP];
  __shared__ __align__(16) f16 Bhs[TN*LDP];
  __shared__ __align__(16) f16 Bls[TN*LDP];
  int tid = threadIdx.x;
  int wave = tid >> 6, lane = tid & 63;
  int wm = wave & 1, wn = wave >> 1;     // 2x2 wave grid, each wave 64x64
  int q = lane >> 4, r = lane & 15;
  size_t bm = (size_t)blockIdx.x * TM;
  size_t bn = (size_t)blockIdx.y * TN;
  f32x4 acc[4][4] = {};
  for (int kk = 0; kk < K; kk += TK){
    // stage A: 128x64 fp32 -> split h/l.  2048 float4 slots, 8 per thread.
    #pragma unroll
    for (int i=0;i<8;i++){
      int g = tid + 256*i;
      int row = g >> 4, c4 = (g & 15) << 2;
      float4 va = *(const float4*)(A + (bm+row)*(size_t)K + kk + c4);
      f16 h0=(f16)va.x, h1=(f16)va.y, h2=(f16)va.z, h3=(f16)va.w;
      f16x4 vh = {h0,h1,h2,h3};
      f16x4 vl = {(f16)(va.x-(float)h0),(f16)(va.y-(float)h1),(f16)(va.z-(float)h2),(f16)(va.w-(float)h3)};
      *(f16x4*)&Ahs[row*LDP + c4] = vh;
      *(f16x4*)&Als[row*LDP + c4] = vl;
    }
    // stage B: 128x64 f16 (h and l).  1024 float4 slots each, 4 per thread.
    #pragma unroll
    for (int i=0;i<4;i++){
      int g = tid + 256*i;
      int row = g >> 3, c8 = (g & 7) << 3;
      *(float4*)&Bhs[row*LDP + c8] = *(const float4*)(BTh + (bn+row)*(size_t)K + kk + c8);
      *(float4*)&Bls[row*LDP + c8] = *(const float4*)(BTl + (bn+row)*(size_t)K + kk + c8);
    }
    __syncthreads();
    #pragma unroll
    for (int ks=0; ks<TK; ks+=32){
      f16x8 ah[4], al[4], bh[4], bl[4];
      #pragma unroll
      for (int i=0;i<4;i++){
        ah[i] = *(const f16x8*)&Ahs[(wm*64 + i*16 + r)*LDP + ks + q*8];
        al[i] = *(const f16x8*)&Als[(wm*64 + i*16 + r)*LDP + ks + q*8];
      }
      #pragma unroll
      for (int j=0;j<4;j++){
        bh[j] = *(const f16x8*)&Bhs[(wn*64 + j*16 + r)*LDP + ks + q*8];
        bl[j] = *(const f16x8*)&Bls[(wn*64 + j*16 + r)*LDP + ks + q*8];
      }
      #pragma unroll
      for (int i=0;i<4;i++)
        #pragma unroll
        for (int j=0;j<4;j++){
          acc[i][j] = __builtin_amdgcn_mfma_f32_16x16x32_f16(ah[i], bh[j], acc[i][j], 0, 0, 0);
          acc[i][j] = __builtin_amdgcn_mfma_f32_16x16x32_f16(ah[i], bl[j], acc[i][j], 0, 0, 0);
          acc[i][j] = __builtin_amdgcn_mfma_f32_16x16x32_f16(al[i], bh[j], acc[i][j], 0, 0, 0);
        }
    }
    __syncthreads();
  }
  #pragma unroll
  for (int i=0;i<4;i++){
    #pragma unroll
    for (int j=0;j<4;j++){
      int col = (int)bn + wn*64 + j*16 + r;
      float badd = bias ? bias[col] : 0.f;
      #pragma unroll
      for (int reg=0; reg<4; reg++){
        int row = (int)bm + wm*64 + i*16 + q*4 + reg;
        float v = acc[i][j][reg] + badd;
        if (rowadd) v += rowadd[(size_t)(row>>7)*N + col];
        if (relu)   v = fmaxf(v, 0.f);
        C[(size_t)row*N + col] = v;
      }
    }
  }
}

// ---------- narrow heads from X[M,256] f32: sigma (+ mus,sigs if Wm) ----------
__global__ void k_headsA(const float* __restrict__ X, const float* __restrict__ Ws,
                         const float* __restrict__ bs, const float* __restrict__ Wm,
                         const float* __restrict__ bm, float* __restrict__ sigma,
                         float* __restrict__ mus, float* __restrict__ sigs,
                         int M, size_t gbase){
  int wid = (blockIdx.x*blockDim.x + threadIdx.x) >> 6;
  int lane = threadIdx.x & 63;
  if (wid >= M) return;
  const float* x = X + (size_t)wid*256;
  float s0=0.f,s1=0.f,s2=0.f;
  for (int k=lane;k<256;k+=64){
    float xv = x[k];
    s0 = fmaf(xv, Ws[k], s0);
    if (Wm){ s1 = fmaf(xv, Wm[2*k], s1); s2 = fmaf(xv, Wm[2*k+1], s2); }
  }
  #pragma unroll
  for (int off=32; off>0; off>>=1){
    s0 += __shfl_down(s0, off);
    s1 += __shfl_down(s1, off);
    s2 += __shfl_down(s2, off);
  }
  if (lane==0){
    sigma[gbase+wid] = s0 + bs[0];
    if (Wm){ mus[gbase+wid] = s1 + bm[0]; sigs[gbase+wid] = s2 + bm[1]; }
  }
}

// ---------- rgb head from h[M,128] f32 ----------
__global__ void k_headsB(const float* __restrict__ H, const float* __restrict__ Wr,
                         const float* __restrict__ br, float* __restrict__ rgbs,
                         int M, size_t gbase){
  int wid = (blockIdx.x*blockDim.x + threadIdx.x) >> 6;
  int lane = threadIdx.x & 63;
  if (wid >= M) return;
  const float* h = H + (size_t)wid*128;
  float s0=0.f,s1=0.f,s2=0.f;
  for (int k=lane;k<128;k+=64){
    float hv = h[k];
    s0 = fmaf(hv, Wr[3*k  ], s0);
    s1 = fmaf(hv, Wr[3*k+1], s1);
    s2 = fmaf(hv, Wr[3*k+2], s2);
  }
  #pragma unroll
  for (int off=32; off>0; off>>=1){
    s0 += __shfl_down(s0, off);
    s1 += __shfl_down(s1, off);
    s2 += __shfl_down(s2, off);
  }
  if (lane==0){
    rgbs[(gbase+wid)*3  ] = s0 + br[0];
    rgbs[(gbase+wid)*3+1] = s1 + br[1];
    rgbs[(gbase+wid)*3+2] = s2 + br[2];
  }
}

// ---------- coarse volume render + inverse-CDF fine sampling (one block per ray) ----------
__global__ __launch_bounds__(256) void k_vr_coarse(
    const float* __restrict__ sigmaC, const float* __restrict__ rgbsC,
    const float* __restrict__ musRaw, const float* __restrict__ sigsRaw,
    const float* __restrict__ rd, float* __restrict__ out_rgbc,
    float* __restrict__ tfine){
  int ray = blockIdx.x, tid = threadIdx.x;
  __shared__ float sh_w[128], sh_pdf[128], sh_cdf[129], sh_lt[128], sh_pib[128], sh_mu[128], sh_sg[128];
  __shared__ float red[256];
  __shared__ float s_wsum;
  float rx = rd[ray*3], ry = rd[ray*3+1], rz = rd[ray*3+2];
  float rn = sqrtf(rx*rx+ry*ry+rz*rz);
  if (tid < 128){
    float sg = fmaxf(sigmaC[(size_t)ray*128+tid], 0.f);
    float alpha = 1.f - expf(-sg * (0.03125f*rn));
    sh_w[tid] = alpha;
    float mu = sigmoidf(musRaw[(size_t)ray*128+tid]);
    float sig = sigmoidf(sigsRaw[(size_t)ray*128+tid]) + 0.001f;
    float sm = 2.f*sig;
    sh_mu[tid]=mu; sh_sg[tid]=sm;
    float lt = approx_cdf_f((0.f-mu)/sm);
    sh_lt[tid]=lt;
    sh_pib[tid]=approx_cdf_f((1.f-mu)/sm) - lt;
  }
  __syncthreads();
  if (tid == 0){
    float T = 1.f;
    for (int s=0;s<128;s++){ float a=sh_w[s]; sh_w[s]=a*T; T *= (1.f-a+1e-10f); }
  }
  __syncthreads();
  for (int ch=0; ch<3; ch++){
    float v = 0.f;
    if (tid<128) v = sh_w[tid]*sigmoidf(rgbsC[((size_t)ray*128+tid)*3+ch]);
    red[tid]=v; __syncthreads();
    for (int o=128;o>0;o>>=1){ if (tid<o) red[tid]+=red[tid+o]; __syncthreads(); }
    if (tid==0) out_rgbc[ray*3+ch] = red[0];
    __syncthreads();
  }
  { float v = (tid<128)? (sh_w[tid]+1e-5f) : 0.f;
    red[tid]=v; __syncthreads();
    for (int o=128;o>0;o>>=1){ if (tid<o) red[tid]+=red[tid+o]; __syncthreads(); }
    if (tid==0) s_wsum = red[0];
    __syncthreads(); }
  if (tid<128) sh_pdf[tid] = (sh_w[tid]+1e-5f)/s_wsum;
  __syncthreads();
  if (tid==0){
    float c=0.f; sh_cdf[0]=0.f;
    for (int s=0;s<128;s++){ c += sh_pdf[s]; sh_cdf[s+1]=c; }
  }
  __syncthreads();
  if (tid < 129){
    float u = (float)tid * ((1.f-1e-5f)/128.f);
    int lo=0, hi=129;
    while (lo<hi){ int mid=(lo+hi)>>1; if (sh_cdf[mid] <= u) lo=mid+1; else hi=mid; }
    int idx = lo-1; idx = idx<0?0:(idx>127?127:idx);
    float frac = (u - sh_cdf[idx]) / fmaxf(sh_pdf[idx], 1e-10f);
    frac = fminf(fmaxf(frac,0.f),1.f);
    float p = sh_lt[idx] + frac*sh_pib[idx];
    p = fminf(fmaxf(p, 1e-5f), 1.f-1e-5f);
    float xx = sh_mu[idx] + sh_sg[idx]*1.4142135623730951f*erfinvf_dev(2.f*p-1.f);
    xx = fminf(fmaxf(xx,0.f),1.f);
    float b0 = 2.f + 0.03125f*(float)idx;
    tfine[(size_t)ray*129+tid] = b0 + xx*0.03125f;
  }
}

// ---------- fine volume render: rgb_f, depth_f, acc_f ----------
__global__ __launch_bounds__(256) void k_vr_fine(
    const float* __restrict__ sigmaF, const float* __restrict__ rgbsF,
    const float* __restrict__ tfine, const float* __restrict__ rd,
    float* __restrict__ dout){
  int ray=blockIdx.x, tid=threadIdx.x;
  __shared__ float sh_w[128], sh_tm[128];
  __shared__ float red[256];
  float rx=rd[ray*3], ry=rd[ray*3+1], rz=rd[ray*3+2];
  float rn = sqrtf(rx*rx+ry*ry+rz*rz);
  if (tid<128){
    float t0=tfine[(size_t)ray*129+tid], t1=tfine[(size_t)ray*129+tid+1];
    float sg=fmaxf(sigmaF[(size_t)ray*128+tid],0.f);
    float alpha = 1.f-expf(-sg*(t1-t0)*rn);
    sh_w[tid]=alpha;
    sh_tm[tid]=0.5f*(t0+t1);
  }
  __syncthreads();
  if (tid==0){ float T=1.f; for(int s=0;s<128;s++){ float a=sh_w[s]; sh_w[s]=a*T; T*=(1.f-a+1e-10f);} }
  __syncthreads();
  for (int ch=0; ch<3; ch++){
    float v=0.f;
    if (tid<128) v = sh_w[tid]*sigmoidf(rgbsF[((size_t)ray*128+tid)*3+ch]);
    red[tid]=v; __syncthreads();
    for(int o=128;o>0;o>>=1){ if(tid<o) red[tid]+=red[tid+o]; __syncthreads(); }
    if (tid==0) dout[NRAYS*3 + ray*3 + ch] = red[0];
    __syncthreads();
  }
  { float v = (tid<128)? sh_w[tid]*sh_tm[tid] : 0.f;
    red[tid]=v; __syncthreads();
    for(int o=128;o>0;o>>=1){ if(tid<o) red[tid]+=red[tid+o]; __syncthreads(); }
    if (tid==0) dout[NRAYS*6 + ray] = red[0];
    __syncthreads(); }
  { float v = (tid<128)? sh_w[tid] : 0.f;
    red[tid]=v; __syncthreads();
    for(int o=128;o>0;o>>=1){ if(tid<o) red[tid]+=red[tid+o]; __syncthreads(); }
    if (tid==0) dout[NRAYS*7 + ray] = red[0]; }
}

extern "C" void kernel_launch(void* const* d_in, const int* in_sizes, int n_in,
                              void* d_out, int out_size, void* d_ws, size_t ws_size,
                              hipStream_t stream) {
  const float* ro  = (const float*)d_in[0];
  const float* rd  = (const float*)d_in[1];
  const float* rr  = (const float*)d_in[2];
  const float* cW0 = (const float*)d_in[3];  const float* cb0 = (const float*)d_in[4];
  const float* cWh = (const float*)d_in[5];  const float* cbh = (const float*)d_in[6];
  const float* cWs = (const float*)d_in[7];  const float* cbs = (const float*)d_in[8];
  const float* cWb = (const float*)d_in[9];  const float* cbb = (const float*)d_in[10];
  const float* cWd = (const float*)d_in[11]; const float* cbd = (const float*)d_in[12];
  const float* cWr = (const float*)d_in[13]; const float* cbr = (const float*)d_in[14];
  int iWm = 27, ibm = 28, ifb = 15;
  if (n_in > 15 && in_sizes[15] == 512){ iWm = 15; ibm = 16; ifb = 17; }
  const float* fW0 = (const float*)d_in[ifb+0];  const float* fb0 = (const float*)d_in[ifb+1];
  const float* fWh = (const float*)d_in[ifb+2];  const float* fbh = (const float*)d_in[ifb+3];
  const float* fWs = (const float*)d_in[ifb+4];  const float* fbs = (const float*)d_in[ifb+5];
  const float* fWb = (const float*)d_in[ifb+6];  const float* fbb = (const float*)d_in[ifb+7];
  const float* fWd = (const float*)d_in[ifb+8];  const float* fbd = (const float*)d_in[ifb+9];
  const float* fWr = (const float*)d_in[ifb+10]; const float* fbr = (const float*)d_in[ifb+11];
  const float* cWm = (const float*)d_in[iWm];    const float* cbm = (const float*)d_in[ibm];

  char* base = (char*)d_ws;
  size_t off = 0;
  auto alloc = [&](size_t bytes)->void*{ off = (off+63) & ~(size_t)63; void* p = base+off; off += bytes; return p; };

  float* direnc  = (float*)alloc((size_t)NRAYS*27*4);
  float* dctrC   = (float*)alloc((size_t)NRAYS*128*4);
  float* dctrF   = (float*)alloc((size_t)NRAYS*128*4);
  float* sigmaC  = (float*)alloc((size_t)NS_TOT*4);
  float* musRaw  = (float*)alloc((size_t)NS_TOT*4);
  float* sigsRaw = (float*)alloc((size_t)NS_TOT*4);
  float* rgbsC   = (float*)alloc((size_t)NS_TOT*3*4);
  float* tfine   = (float*)alloc((size_t)NRAYS*129*4);
  float* sigmaF  = (float*)alloc((size_t)NS_TOT*4);
  float* rgbsF   = (float*)alloc((size_t)NS_TOT*3*4);

  // split weights: h and l for each
  f16 *cW0h=(f16*)alloc((size_t)256*128*2), *cW0l=(f16*)alloc((size_t)256*128*2);
  f16 *cWhh=(f16*)alloc((size_t)3*256*256*2), *cWhl=(f16*)alloc((size_t)3*256*256*2);
  f16 *cWbh=(f16*)alloc((size_t)256*256*2), *cWbl=(f16*)alloc((size_t)256*256*2);
  f16 *cWdh=(f16*)alloc((size_t)128*256*2), *cWdl=(f16*)alloc((size_t)128*256*2);
  f16 *fW0h=(f16*)alloc((size_t)256*128*2), *fW0l=(f16*)alloc((size_t)256*128*2);
  f16 *fWhh=(f16*)alloc((size_t)3*256*256*2), *fWhl=(f16*)alloc((size_t)3*256*256*2);
  f16 *fWbh=(f16*)alloc((size_t)256*256*2), *fWbl=(f16*)alloc((size_t)256*256*2);
  f16 *fWdh=(f16*)alloc((size_t)128*256*2), *fWdl=(f16*)alloc((size_t)128*256*2);

  // chunk region (fp32 activations): per-ray = 128*(128+256+256+128)*4 bytes
  off = (off+63) & ~(size_t)63;
  size_t remain = (ws_size > off) ? (ws_size - off) : 0;
  const size_t perRayB = (size_t)128*(128+256+256+128)*4;
  int R = (int)(remain / perRayB);
  if (R > NRAYS) R = NRAYS;
  if (R < 1) R = 1;
  float* encB = (float*)(base + off);
  float* ping = encB + (size_t)R*128*128;
  float* pong = ping + (size_t)R*128*256;
  float* hbuf = pong + (size_t)R*128*256;

  // ---- weight conversion+split (once per launch) ----
  k_cvtT<<<(256*128+255)/256,256,0,stream>>>(cW0, cW0h, cW0l, 96, 256, 128);
  for (int i=0;i<3;i++)
    k_cvtT<<<(256*256+255)/256,256,0,stream>>>(cWh+(size_t)i*65536, cWhh+(size_t)i*65536, cWhl+(size_t)i*65536, 256, 256, 256);
  k_cvtT<<<(256*256+255)/256,256,0,stream>>>(cWb, cWbh, cWbl, 256, 256, 256);
  k_cvtT<<<(128*256+255)/256,256,0,stream>>>(cWd, cWdh, cWdl, 256, 128, 256);
  k_cvtT<<<(256*128+255)/256,256,0,stream>>>(fW0, fW0h, fW0l, 96, 256, 128);
  for (int i=0;i<3;i++)
    k_cvtT<<<(256*256+255)/256,256,0,stream>>>(fWh+(size_t)i*65536, fWhh+(size_t)i*65536, fWhl+(size_t)i*65536, 256, 256, 256);
  k_cvtT<<<(256*256+255)/256,256,0,stream>>>(fWb, fWbh, fWbl, 256, 256, 256);
  k_cvtT<<<(128*256+255)/256,256,0,stream>>>(fWd, fWdh, fWdl, 256, 128, 256);

  k_setup<<<(NRAYS+255)/256, 256, 0, stream>>>(rd, direnc);
  k_dctr<<<(NRAYS*128)/256, 256, 0, stream>>>(direnc, cWd, cbd, dctrC);
  k_dctr<<<(NRAYS*128)/256, 256, 0, stream>>>(direnc, fWd, fbd, dctrF);

  // ---- coarse MLP ----
  for (int basei=0; basei<NRAYS; basei+=R){
    int rays = (NRAYS-basei < R) ? (NRAYS-basei) : R;
    int Mc = rays*128;
    dim3 g2(Mc/128, 2), g1(Mc/128, 1);
    k_enc<<<(Mc+255)/256, 256, 0, stream>>>(ro, rd, rr, nullptr, encB, basei, Mc);
    k_gemm_split<<<g2,256,0,stream>>>(encB, cW0h, cW0l, cb0, nullptr, ping, Mc,256,128, 1);
    k_gemm_split<<<g2,256,0,stream>>>(ping, cWhh,        cWhl,        cbh,     nullptr, pong, Mc,256,256, 1);
    k_gemm_split<<<g2,256,0,stream>>>(pong, cWhh+65536,  cWhl+65536,  cbh+256, nullptr, ping, Mc,256,256, 1);
    k_gemm_split<<<g2,256,0,stream>>>(ping, cWhh+131072, cWhl+131072, cbh+512, nullptr, pong, Mc,256,256, 1);
    k_headsA<<<Mc/4,256,0,stream>>>(pong, cWs, cbs, cWm, cbm, sigmaC, musRaw, sigsRaw, Mc, (size_t)basei*128);
    k_gemm_split<<<g2,256,0,stream>>>(pong, cWbh, cWbl, cbb, nullptr, ping, Mc,256,256, 0);
    k_gemm_split<<<g1,256,0,stream>>>(ping, cWdh, cWdl, nullptr, dctrC+(size_t)basei*128, hbuf, Mc,128,256, 1);
    k_headsB<<<Mc/4,256,0,stream>>>(hbuf, cWr, cbr, rgbsC, Mc, (size_t)basei*128);
  }
  k_vr_coarse<<<NRAYS,256,0,stream>>>(sigmaC, rgbsC, musRaw, sigsRaw, rd, (float*)d_out, tfine);

  // ---- fine MLP ----
  for (int basei=0; basei<NRAYS; basei+=R){
    int rays = (NRAYS-basei < R) ? (NRAYS-basei) : R;
    int Mc = rays*128;
    dim3 g2(Mc/128, 2), g1(Mc/128, 1);
    k_enc<<<(Mc+255)/256, 256, 0, stream>>>(ro, rd, rr, tfine, encB, basei, Mc);
    k_gemm_split<<<g2,256,0,stream>>>(encB, fW0h, fW0l, fb0, nullptr, ping, Mc,256,128, 1);
    k_gemm_split<<<g2,256,0,stream>>>(ping, fWhh,        fWhl,        fbh,     nullptr, pong, Mc,256,256, 1);
    k_gemm_split<<<g2,256,0,stream>>>(pong, fWhh+65536,  fWhl+65536,  fbh+256, nullptr, ping, Mc,256,256, 1);
    k_gemm_split<<<g2,256,0,stream>>>(ping, fWhh+131072, fWhl+131072, fbh+512, nullptr, pong, Mc,256,256, 1);
    k_headsA<<<Mc/4,256,0,stream>>>(pong, fWs, fbs, nullptr, nullptr, sigmaF, nullptr, nullptr, Mc, (size_t)basei*128);
    k_gemm_split<<<g2,256,0,stream>>>(pong, fWbh, fWbl, fbb, nullptr, ping, Mc,256,256, 0);
    k_gemm_split<<<g1,256,0,stream>>>(ping, fWdh, fWdl, nullptr, dctrF+(size_t)basei*128, hbuf, Mc,128,256, 1);
    k_headsB<<<Mc/4,256,0,stream>>>(hbuf, fWr, fbr, rgbsF, Mc, (size_t)basei*128);
  }
  k_vr_fine<<<NRAYS,256,0,stream>>>(sigmaF, rgbsF, tfine, rd, (float*)d_out);
}

// Round 5
// 1604.401 us; speedup vs baseline: 5.2793x; 1.9780x over previous
//
#include <hip/hip_runtime.h>

#define NRAYS 2048
#define LP 264   // LDS activation pitch in f16 elems (528B rows: 16B-aligned, 2-way bank alias = free)

typedef _Float16 f16;
typedef __attribute__((ext_vector_type(8))) _Float16 f16x8;
typedef __attribute__((ext_vector_type(4))) float f32x4;

__device__ __forceinline__ float sigmoidf(float x){ return 1.f/(1.f+expf(-x)); }

__device__ __forceinline__ float approx_cdf_f(float x){
  return 0.5f*(1.f + tanhf(0.7978845608028654f*(x + 0.044715f*x*x*x)));
}

// Giles (2010) single-precision erfinv, max rel err ~1e-6
__device__ __forceinline__ float erfinvf_dev(float x){
  float w = -logf((1.0f-x)*(1.0f+x));
  float p;
  if (w < 5.0f){
    w -= 2.5f;
    p = 2.81022636e-08f;
    p = fmaf(p,w, 3.43273939e-07f);
    p = fmaf(p,w,-3.5233877e-06f);
    p = fmaf(p,w,-4.39150654e-06f);
    p = fmaf(p,w, 0.00021858087f);
    p = fmaf(p,w,-0.00125372503f);
    p = fmaf(p,w,-0.00417768164f);
    p = fmaf(p,w, 0.246640727f);
    p = fmaf(p,w, 1.50140941f);
  } else {
    w = sqrtf(w) - 3.0f;
    p = -0.000200214257f;
    p = fmaf(p,w, 0.000100950558f);
    p = fmaf(p,w, 0.00134934322f);
    p = fmaf(p,w,-0.00367342844f);
    p = fmaf(p,w, 0.00573950773f);
    p = fmaf(p,w,-0.0076224613f);
    p = fmaf(p,w, 0.00943887047f);
    p = fmaf(p,w, 1.00167406f);
    p = fmaf(p,w, 2.83297682f);
  }
  return p*x;
}

// ---------- weight convert+transpose+split: W[Ksrc][N] f32 -> Wh/Wl[N][Kdst] f16 ----------
__global__ void k_cvtT(const float* __restrict__ W, f16* __restrict__ Wh, f16* __restrict__ Wl,
                       int Ksrc, int N, int Kdst){
  int g = blockIdx.x*blockDim.x + threadIdx.x;
  if (g >= N*Kdst) return;
  int n = g / Kdst, k = g - n*Kdst;
  float v = (k < Ksrc) ? W[(size_t)k*N + n] : 0.f;
  f16 h = (f16)v;
  Wh[g] = h;
  Wl[g] = (f16)(v - (float)h);
}

struct Weights {
  const f16 *W0h,*W0l; const float *b0;
  const f16 *Whh,*Whl; const float *bh;
  const float *Ws,*bs,*Wm,*bm;      // Wm,bm only used when coarse
  const f16 *Wbh,*Wbl; const float *bb;
  const f16 *Wdh,*Wdl; const float *Wdfull,*bd;
  const float *Wr,*br;
};

// One layer: X(h+l in LDS, 128 x K) @ BT^T (N x K, split h/l in global/L2) -> back into X.
// 8 waves; wave covers NT*16 output cols. acc = Ah*Bh + Ah*Bl + Al*Bh (fp32).
template<int K, int NT>
__device__ __forceinline__ void mlp_layer(
    f16 (&Xh)[128*LP], f16 (&Xl)[128*LP],
    const f16* __restrict__ Bh, const f16* __restrict__ Bl,
    const float* __restrict__ bias, const float* dctr, int relu,
    int wave, int q, int r)
{
  const int nbase = wave * (NT*16);
  f32x4 acc[8][NT];
  #pragma unroll
  for (int m=0;m<8;m++)
    #pragma unroll
    for (int j=0;j<NT;j++) acc[m][j] = (f32x4){0.f,0.f,0.f,0.f};
  #pragma unroll
  for (int k0=0;k0<K;k0+=32){
    f16x8 bh[NT], bl[NT];
    #pragma unroll
    for (int j=0;j<NT;j++){
      size_t o = (size_t)(nbase + j*16 + r)*K + k0 + q*8;
      bh[j] = *(const f16x8*)(Bh + o);
      bl[j] = *(const f16x8*)(Bl + o);
    }
    #pragma unroll
    for (int m=0;m<8;m++){
      int ao = (m*16 + r)*LP + k0 + q*8;
      f16x8 ah = *(const f16x8*)&Xh[ao];
      f16x8 al = *(const f16x8*)&Xl[ao];
      #pragma unroll
      for (int j=0;j<NT;j++){
        acc[m][j] = __builtin_amdgcn_mfma_f32_16x16x32_f16(ah, bh[j], acc[m][j], 0,0,0);
        acc[m][j] = __builtin_amdgcn_mfma_f32_16x16x32_f16(ah, bl[j], acc[m][j], 0,0,0);
        acc[m][j] = __builtin_amdgcn_mfma_f32_16x16x32_f16(al, bh[j], acc[m][j], 0,0,0);
      }
    }
  }
  __syncthreads();   // all waves done reading X
  #pragma unroll
  for (int m=0;m<8;m++){
    #pragma unroll
    for (int j=0;j<NT;j++){
      int col = nbase + j*16 + r;
      float ba = bias ? bias[col] : 0.f;
      float da = dctr ? dctr[col] : 0.f;
      #pragma unroll
      for (int reg=0;reg<4;reg++){
        int row = m*16 + q*4 + reg;
        float v = acc[m][j][reg] + ba + da;
        if (relu) v = fmaxf(v, 0.f);
        f16 h = (f16)v;
        Xh[row*LP + col] = h;
        Xl[row*LP + col] = (f16)(v - (float)h);
      }
    }
  }
  __syncthreads();
}

// ---------- fully fused pass: enc + MLP + heads + volume render (1 block = 1 ray) ----------
__global__ __launch_bounds__(512,2) void k_fused(
    const float* __restrict__ ro, const float* __restrict__ rd, const float* __restrict__ rr,
    Weights w, const float* __restrict__ tfine_in, float* __restrict__ tfine_out,
    float* __restrict__ dout, int coarse)
{
  __shared__ f16 Xh[128*LP];
  __shared__ f16 Xl[128*LP];
  __shared__ float sh_t[132];
  __shared__ float sh_de[32];
  __shared__ float sh_dctr[128];
  __shared__ float sh_sig[128], sh_mu[128], sh_sgm[128];
  __shared__ float sh_rgb[3*128];
  __shared__ float red[256];
  __shared__ float sh_w[128], sh_pdf[128], sh_cdf[132], sh_lt[128], sh_pib[128];
  __shared__ float s_wsum;

  int ray = blockIdx.x, tid = threadIdx.x;
  int wave = tid>>6, lane = tid&63, q = lane>>4, r = lane&15;

  float rdx = rd[ray*3], rdy = rd[ray*3+1], rdz = rd[ray*3+2];
  float rn = sqrtf(rdx*rdx+rdy*rdy+rdz*rdz);

  // t bins
  if (coarse){
    if (tid <= 128) sh_t[tid] = 2.f + 4.f*(float)tid/128.f;
  } else {
    if (tid <= 128) sh_t[tid] = tfine_in[(size_t)ray*129 + tid];
  }
  // direnc (27 values)
  if (tid < 27){
    float v0=rdx/rn, v1=rdy/rn, v2=rdz/rn;
    float vv[3] = {v0,v1,v2};
    float o;
    if (tid < 3) o = vv[tid];
    else if (tid < 15){ int f=(tid-3)/3, j=(tid-3)%3; o = sinf(vv[j]*(float)(1<<f)); }
    else            { int f=(tid-15)/3, j=(tid-15)%3; o = cosf(vv[j]*(float)(1<<f)); }
    sh_de[tid] = o;
  }
  __syncthreads();

  // enc: sample s = tid>>2, part p = tid&3 handles freqs p*4..p*4+3 (all 3 axes)
  {
    int s = tid >> 2, p = tid & 3;
    float t0 = sh_t[s], t1 = sh_t[s+1];
    float c = 0.5f*(t0+t1), d = 0.5f*(t1-t0);
    float c2 = c*c, d2 = d*d;
    float denom = 3.f*c2 + d2;
    float t_mean = c + 2.f*c*d2/denom;
    float d4 = d2*d2;
    float t_var = d2*(1.f/3.f) - (4.f/15.f)*(d4*(12.f*c2 - d2))/(denom*denom);
    float rrv = rr[ray];
    float r_var = rrv*rrv*(c2*0.25f + (5.f/12.f)*d2 - (4.f/15.f)*d4/denom);
    float rdv[3] = {rdx, rdy, rdz};
    float rov[3] = {ro[ray*3], ro[ray*3+1], ro[ray*3+2]};
    float dd = rdx*rdx+rdy*rdy+rdz*rdz;
    float invdd = 1.f/fmaxf(dd, 1e-10f);
    #pragma unroll
    for (int j=0;j<3;j++){
      float mean = rov[j] + rdv[j]*t_mean;
      float doj = rdv[j]*rdv[j];
      float cov = t_var*doj + r_var*(1.f - doj*invdd);
      #pragma unroll
      for (int kk=p*4; kk<p*4+4; kk++){
        float sc = (float)(1<<kk);
        float att = expf(-0.5f*cov*sc*sc);
        float sv, cv;
        sincosf(mean*sc, &sv, &cv);
        float a0 = sv*att, a1 = cv*att;
        f16 h0=(f16)a0, h1=(f16)a1;
        int i0 = s*LP + kk*3 + j, i1 = s*LP + 48 + kk*3 + j;
        Xh[i0]=h0; Xl[i0]=(f16)(a0-(float)h0);
        Xh[i1]=h1; Xl[i1]=(f16)(a1-(float)h1);
      }
    }
    // zero-pad cols 96..127
    #pragma unroll
    for (int i=0;i<8;i++){
      int col = 96 + p*8 + i;
      Xh[s*LP+col]=(f16)0.f; Xl[s*LP+col]=(f16)0.f;
    }
  }
  __syncthreads();

  // dctr[j] = bd[j] + direnc . Wd[256:283, j]  (fp32; runs concurrent with L0 k-loop)
  if (tid < 128){
    float acc = w.bd[tid];
    #pragma unroll
    for (int k=0;k<27;k++) acc = fmaf(sh_de[k], w.Wdfull[(size_t)(256+k)*128 + tid], acc);
    sh_dctr[tid] = acc;
  }

  // ---- MLP trunk ----
  mlp_layer<128,2>(Xh,Xl, w.W0h, w.W0l, w.b0, nullptr, 1, wave,q,r);
  mlp_layer<256,2>(Xh,Xl, w.Whh,          w.Whl,          w.bh,      nullptr, 1, wave,q,r);
  mlp_layer<256,2>(Xh,Xl, w.Whh+65536,    w.Whl+65536,    w.bh+256,  nullptr, 1, wave,q,r);
  mlp_layer<256,2>(Xh,Xl, w.Whh+131072,   w.Whl+131072,   w.bh+512,  nullptr, 1, wave,q,r);

  // sigma head (+ mus/sigs when coarse) from x = X
  if (tid < 128){
    int rowo = tid*LP;
    float s0=0.f, s1=0.f, s2=0.f;
    for (int k=0;k<256;k++){
      float xv = (float)Xh[rowo+k] + (float)Xl[rowo+k];
      s0 = fmaf(xv, w.Ws[k], s0);
      if (coarse){ s1 = fmaf(xv, w.Wm[2*k], s1); s2 = fmaf(xv, w.Wm[2*k+1], s2); }
    }
    sh_sig[tid] = s0 + w.bs[0];
    if (coarse){
      sh_mu[tid]  = sigmoidf(s1 + w.bm[0]);
      sh_sgm[tid] = 2.f*(sigmoidf(s2 + w.bm[1]) + 0.001f);
    }
  }

  // bottleneck (no relu) then Wd layer (adds dctr, relu, writes cols 0..127)
  mlp_layer<256,2>(Xh,Xl, w.Wbh, w.Wbl, w.bb, nullptr, 0, wave,q,r);
  mlp_layer<256,1>(Xh,Xl, w.Wdh, w.Wdl, nullptr, sh_dctr, 1, wave,q,r);

  // rgb head from h = X[:,0:128]
  if (tid < 128){
    int rowo = tid*LP;
    float s0=0.f,s1=0.f,s2=0.f;
    for (int k=0;k<128;k++){
      float hv = (float)Xh[rowo+k] + (float)Xl[rowo+k];
      s0 = fmaf(hv, w.Wr[3*k  ], s0);
      s1 = fmaf(hv, w.Wr[3*k+1], s1);
      s2 = fmaf(hv, w.Wr[3*k+2], s2);
    }
    sh_rgb[tid*3  ] = s0 + w.br[0];
    sh_rgb[tid*3+1] = s1 + w.br[1];
    sh_rgb[tid*3+2] = s2 + w.br[2];
  }
  __syncthreads();

  // ---- volume render ----
  if (coarse){
    if (tid < 128){
      float sg = fmaxf(sh_sig[tid], 0.f);
      float alpha = 1.f - expf(-sg * (0.03125f*rn));
      sh_w[tid] = alpha;
      float mu = sh_mu[tid], sm = sh_sgm[tid];
      float lt = approx_cdf_f((0.f-mu)/sm);
      sh_lt[tid] = lt;
      sh_pib[tid] = approx_cdf_f((1.f-mu)/sm) - lt;
    }
    __syncthreads();
    if (tid == 0){
      float T = 1.f;
      for (int s=0;s<128;s++){ float a=sh_w[s]; sh_w[s]=a*T; T *= (1.f-a+1e-10f); }
    }
    __syncthreads();
    for (int ch=0; ch<3; ch++){
      if (tid < 256) red[tid] = (tid<128)? sh_w[tid]*sigmoidf(sh_rgb[tid*3+ch]) : 0.f;
      __syncthreads();
      for (int o=128;o>0;o>>=1){ if (tid<o) red[tid]+=red[tid+o]; __syncthreads(); }
      if (tid==0) dout[ray*3+ch] = red[0];
      __syncthreads();
    }
    if (tid < 256) red[tid] = (tid<128)? (sh_w[tid]+1e-5f) : 0.f;
    __syncthreads();
    for (int o=128;o>0;o>>=1){ if (tid<o) red[tid]+=red[tid+o]; __syncthreads(); }
    if (tid==0) s_wsum = red[0];
    __syncthreads();
    if (tid<128) sh_pdf[tid] = (sh_w[tid]+1e-5f)/s_wsum;
    __syncthreads();
    if (tid==0){
      float c=0.f; sh_cdf[0]=0.f;
      for (int s=0;s<128;s++){ c += sh_pdf[s]; sh_cdf[s+1]=c; }
    }
    __syncthreads();
    if (tid < 129){
      float u = (float)tid * ((1.f-1e-5f)/128.f);
      int lo=0, hi=129;
      while (lo<hi){ int mid=(lo+hi)>>1; if (sh_cdf[mid] <= u) lo=mid+1; else hi=mid; }
      int idx = lo-1; idx = idx<0?0:(idx>127?127:idx);
      float frac = (u - sh_cdf[idx]) / fmaxf(sh_pdf[idx], 1e-10f);
      frac = fminf(fmaxf(frac,0.f),1.f);
      float p = sh_lt[idx] + frac*sh_pib[idx];
      p = fminf(fmaxf(p, 1e-5f), 1.f-1e-5f);
      float xx = sh_mu[idx] + sh_sgm[idx]*1.4142135623730951f*erfinvf_dev(2.f*p-1.f);
      xx = fminf(fmaxf(xx,0.f),1.f);
      float b0 = 2.f + 0.03125f*(float)idx;
      tfine_out[(size_t)ray*129+tid] = b0 + xx*0.03125f;
    }
  } else {
    if (tid < 128){
      float t0=sh_t[tid], t1=sh_t[tid+1];
      float sg = fmaxf(sh_sig[tid], 0.f);
      sh_w[tid] = 1.f - expf(-sg*(t1-t0)*rn);
    }
    __syncthreads();
    if (tid==0){
      float T=1.f;
      for (int s=0;s<128;s++){ float a=sh_w[s]; sh_w[s]=a*T; T*=(1.f-a+1e-10f); }
    }
    __syncthreads();
    for (int ch=0; ch<3; ch++){
      if (tid < 256) red[tid] = (tid<128)? sh_w[tid]*sigmoidf(sh_rgb[tid*3+ch]) : 0.f;
      __syncthreads();
      for (int o=128;o>0;o>>=1){ if (tid<o) red[tid]+=red[tid+o]; __syncthreads(); }
      if (tid==0) dout[NRAYS*3 + ray*3 + ch] = red[0];
      __syncthreads();
    }
    if (tid < 256) red[tid] = (tid<128)? sh_w[tid]*0.5f*(sh_t[tid]+sh_t[tid+1]) : 0.f;
    __syncthreads();
    for (int o=128;o>0;o>>=1){ if (tid<o) red[tid]+=red[tid+o]; __syncthreads(); }
    if (tid==0) dout[NRAYS*6 + ray] = red[0];
    __syncthreads();
    if (tid < 256) red[tid] = (tid<128)? sh_w[tid] : 0.f;
    __syncthreads();
    for (int o=128;o>0;o>>=1){ if (tid<o) red[tid]+=red[tid+o]; __syncthreads(); }
    if (tid==0) dout[NRAYS*7 + ray] = red[0];
  }
}

extern "C" void kernel_launch(void* const* d_in, const int* in_sizes, int n_in,
                              void* d_out, int out_size, void* d_ws, size_t ws_size,
                              hipStream_t stream) {
  const float* ro  = (const float*)d_in[0];
  const float* rd  = (const float*)d_in[1];
  const float* rr  = (const float*)d_in[2];
  const float* cW0 = (const float*)d_in[3];  const float* cb0 = (const float*)d_in[4];
  const float* cWh = (const float*)d_in[5];  const float* cbh = (const float*)d_in[6];
  const float* cWs = (const float*)d_in[7];  const float* cbs = (const float*)d_in[8];
  const float* cWb = (const float*)d_in[9];  const float* cbb = (const float*)d_in[10];
  const float* cWd = (const float*)d_in[11]; const float* cbd = (const float*)d_in[12];
  const float* cWr = (const float*)d_in[13]; const float* cbr = (const float*)d_in[14];
  int iWm = 27, ibm = 28, ifb = 15;
  if (n_in > 15 && in_sizes[15] == 512){ iWm = 15; ibm = 16; ifb = 17; }
  const float* fW0 = (const float*)d_in[ifb+0];  const float* fb0 = (const float*)d_in[ifb+1];
  const float* fWh = (const float*)d_in[ifb+2];  const float* fbh = (const float*)d_in[ifb+3];
  const float* fWs = (const float*)d_in[ifb+4];  const float* fbs = (const float*)d_in[ifb+5];
  const float* fWb = (const float*)d_in[ifb+6];  const float* fbb = (const float*)d_in[ifb+7];
  const float* fWd = (const float*)d_in[ifb+8];  const float* fbd = (const float*)d_in[ifb+9];
  const float* fWr = (const float*)d_in[ifb+10]; const float* fbr = (const float*)d_in[ifb+11];
  const float* cWm = (const float*)d_in[iWm];    const float* cbm = (const float*)d_in[ibm];

  char* base = (char*)d_ws;
  size_t off = 0;
  auto alloc = [&](size_t bytes)->void*{ off = (off+63) & ~(size_t)63; void* p = base+off; off += bytes; return p; };

  float* tfine = (float*)alloc((size_t)NRAYS*129*4);
  f16 *cW0h=(f16*)alloc((size_t)256*128*2), *cW0l=(f16*)alloc((size_t)256*128*2);
  f16 *cWhh=(f16*)alloc((size_t)3*256*256*2), *cWhl=(f16*)alloc((size_t)3*256*256*2);
  f16 *cWbh=(f16*)alloc((size_t)256*256*2), *cWbl=(f16*)alloc((size_t)256*256*2);
  f16 *cWdh=(f16*)alloc((size_t)128*256*2), *cWdl=(f16*)alloc((size_t)128*256*2);
  f16 *fW0h=(f16*)alloc((size_t)256*128*2), *fW0l=(f16*)alloc((size_t)256*128*2);
  f16 *fWhh=(f16*)alloc((size_t)3*256*256*2), *fWhl=(f16*)alloc((size_t)3*256*256*2);
  f16 *fWbh=(f16*)alloc((size_t)256*256*2), *fWbl=(f16*)alloc((size_t)256*256*2);
  f16 *fWdh=(f16*)alloc((size_t)128*256*2), *fWdl=(f16*)alloc((size_t)128*256*2);

  // weight conversion+split (tiny)
  k_cvtT<<<(256*128+255)/256,256,0,stream>>>(cW0, cW0h, cW0l, 96, 256, 128);
  k_cvtT<<<(3*256*256+255)/256,256,0,stream>>>(cWh, cWhh, cWhl, 0, 0, 0); // dummy-safe? no — do per-layer below
  // NOTE: the line above would be wrong; do the three layers explicitly:
  for (int i=0;i<3;i++)
    k_cvtT<<<(256*256+255)/256,256,0,stream>>>(cWh+(size_t)i*65536, cWhh+(size_t)i*65536, cWhl+(size_t)i*65536, 256, 256, 256);
  k_cvtT<<<(256*256+255)/256,256,0,stream>>>(cWb, cWbh, cWbl, 256, 256, 256);
  k_cvtT<<<(128*256+255)/256,256,0,stream>>>(cWd, cWdh, cWdl, 256, 128, 256);
  k_cvtT<<<(256*128+255)/256,256,0,stream>>>(fW0, fW0h, fW0l, 96, 256, 128);
  for (int i=0;i<3;i++)
    k_cvtT<<<(256*256+255)/256,256,0,stream>>>(fWh+(size_t)i*65536, fWhh+(size_t)i*65536, fWhl+(size_t)i*65536, 256, 256, 256);
  k_cvtT<<<(256*256+255)/256,256,0,stream>>>(fWb, fWbh, fWbl, 256, 256, 256);
  k_cvtT<<<(128*256+255)/256,256,0,stream>>>(fWd, fWdh, fWdl, 256, 128, 256);

  Weights wc = { cW0h,cW0l,cb0, cWhh,cWhl,cbh, cWs,cbs,cWm,cbm,
                 cWbh,cWbl,cbb, cWdh,cWdl,cWd,cbd, cWr,cbr };
  Weights wf = { fW0h,fW0l,fb0, fWhh,fWhl,fbh, fWs,fbs,nullptr,nullptr,
                 fWbh,fWbl,fbb, fWdh,fWdl,fWd,fbd, fWr,fbr };

  k_fused<<<NRAYS,512,0,stream>>>(ro, rd, rr, wc, nullptr, tfine, (float*)d_out, 1);
  k_fused<<<NRAYS,512,0,stream>>>(ro, rd, rr, wf, tfine, nullptr, (float*)d_out, 0);
}

// Round 6
// 1419.912 us; speedup vs baseline: 5.9653x; 1.1299x over previous
//
#include <hip/hip_runtime.h>

#define NRAYS 2048
#define LP 264   // LDS activation pitch in f16 elems (528B rows: 16B-aligned, 2-way bank alias = free)

typedef _Float16 f16;
typedef __attribute__((ext_vector_type(8))) _Float16 f16x8;
typedef __attribute__((ext_vector_type(4))) float f32x4;

__device__ __forceinline__ float sigmoidf(float x){ return 1.f/(1.f+expf(-x)); }

__device__ __forceinline__ float approx_cdf_f(float x){
  return 0.5f*(1.f + tanhf(0.7978845608028654f*(x + 0.044715f*x*x*x)));
}

// Giles (2010) single-precision erfinv, max rel err ~1e-6
__device__ __forceinline__ float erfinvf_dev(float x){
  float w = -logf((1.0f-x)*(1.0f+x));
  float p;
  if (w < 5.0f){
    w -= 2.5f;
    p = 2.81022636e-08f;
    p = fmaf(p,w, 3.43273939e-07f);
    p = fmaf(p,w,-3.5233877e-06f);
    p = fmaf(p,w,-4.39150654e-06f);
    p = fmaf(p,w, 0.00021858087f);
    p = fmaf(p,w,-0.00125372503f);
    p = fmaf(p,w,-0.00417768164f);
    p = fmaf(p,w, 0.246640727f);
    p = fmaf(p,w, 1.50140941f);
  } else {
    w = sqrtf(w) - 3.0f;
    p = -0.000200214257f;
    p = fmaf(p,w, 0.000100950558f);
    p = fmaf(p,w, 0.00134934322f);
    p = fmaf(p,w,-0.00367342844f);
    p = fmaf(p,w, 0.00573950773f);
    p = fmaf(p,w,-0.0076224613f);
    p = fmaf(p,w, 0.00943887047f);
    p = fmaf(p,w, 1.00167406f);
    p = fmaf(p,w, 2.83297682f);
  }
  return p*x;
}

// ---------- weight convert+transpose+split: W[Ksrc][N] f32 -> Wh/Wl[N][Kdst] f16 ----------
__global__ void k_cvtT(const float* __restrict__ W, f16* __restrict__ Wh, f16* __restrict__ Wl,
                       int Ksrc, int N, int Kdst){
  int g = blockIdx.x*blockDim.x + threadIdx.x;
  if (g >= N*Kdst) return;
  int n = g / Kdst, k = g - n*Kdst;
  float v = (k < Ksrc) ? W[(size_t)k*N + n] : 0.f;
  f16 h = (f16)v;
  Wh[g] = h;
  Wl[g] = (f16)(v - (float)h);
}

struct Weights {
  const f16 *W0h,*W0l; const float *b0;
  const f16 *Whh,*Whl; const float *bh;
  const float *Ws,*bs,*Wm,*bm;      // Wm,bm only used when coarse
  const f16 *Wbh,*Wbl; const float *bb;
  const f16 *Wdh,*Wdl; const float *Wdfull,*bd;
  const float *Wr,*br;
};

// One layer: X(h+l in LDS, 128 x K) @ BT^T (N x K, split h/l, from L2) -> back into X.
// 8 waves; wave covers NT*16 output cols. acc = Ah*Bh + Ah*Bl + Al*Bh (fp32).
template<int K, int NT>
__device__ __forceinline__ void mlp_layer(
    f16 (&Xh)[128*LP], f16 (&Xl)[128*LP],
    const f16* __restrict__ Bh, const f16* __restrict__ Bl,
    const float* __restrict__ bias, const float* dctr, int relu,
    int wave, int q, int r)
{
  const int nbase = wave * (NT*16);
  f32x4 acc[8][NT];
  #pragma unroll
  for (int m=0;m<8;m++)
    #pragma unroll
    for (int j=0;j<NT;j++) acc[m][j] = (f32x4){0.f,0.f,0.f,0.f};
  #pragma unroll
  for (int k0=0;k0<K;k0+=32){
    f16x8 bh[NT], bl[NT];
    #pragma unroll
    for (int j=0;j<NT;j++){
      size_t o = (size_t)(nbase + j*16 + r)*K + k0 + q*8;
      bh[j] = *(const f16x8*)(Bh + o);
      bl[j] = *(const f16x8*)(Bl + o);
    }
    #pragma unroll
    for (int m=0;m<8;m++){
      int ao = (m*16 + r)*LP + k0 + q*8;
      f16x8 ah = *(const f16x8*)&Xh[ao];
      f16x8 al = *(const f16x8*)&Xl[ao];
      #pragma unroll
      for (int j=0;j<NT;j++){
        acc[m][j] = __builtin_amdgcn_mfma_f32_16x16x32_f16(ah, bh[j], acc[m][j], 0,0,0);
        acc[m][j] = __builtin_amdgcn_mfma_f32_16x16x32_f16(ah, bl[j], acc[m][j], 0,0,0);
        acc[m][j] = __builtin_amdgcn_mfma_f32_16x16x32_f16(al, bh[j], acc[m][j], 0,0,0);
      }
    }
  }
  __syncthreads();   // all waves done reading X
  #pragma unroll
  for (int m=0;m<8;m++){
    #pragma unroll
    for (int j=0;j<NT;j++){
      int col = nbase + j*16 + r;
      float ba = bias ? bias[col] : 0.f;
      float da = dctr ? dctr[col] : 0.f;
      #pragma unroll
      for (int reg=0;reg<4;reg++){
        int row = m*16 + q*4 + reg;
        float v = acc[m][j][reg] + ba + da;
        if (relu) v = fmaxf(v, 0.f);
        f16 h = (f16)v;
        Xh[row*LP + col] = h;
        Xl[row*LP + col] = (f16)(v - (float)h);
      }
    }
  }
  __syncthreads();
}

// ---------- fully fused pass: enc + MLP + heads + volume render (1 block = 1 ray) ----------
__global__ __launch_bounds__(512,1) void k_fused(
    const float* __restrict__ ro, const float* __restrict__ rd, const float* __restrict__ rr,
    Weights w, const float* __restrict__ tfine_in, float* __restrict__ tfine_out,
    float* __restrict__ dout, int coarse)
{
  __shared__ f16 Xh[128*LP];
  __shared__ f16 Xl[128*LP];
  __shared__ float sh_t[132];
  __shared__ float sh_de[32];
  __shared__ float sh_dctr[128];
  __shared__ float sh_sig[128], sh_mu[128], sh_sgm[128];
  __shared__ float sh_rgb[3*128];
  __shared__ float red[16];
  __shared__ float sh_w[128], sh_pdf[128], sh_cdf[132], sh_lt[128], sh_pib[128];
  __shared__ float s_wsum;

  int ray = blockIdx.x, tid = threadIdx.x;
  int wave = tid>>6, lane = tid&63, q = lane>>4, r = lane&15;

  float rdx = rd[ray*3], rdy = rd[ray*3+1], rdz = rd[ray*3+2];
  float rn = sqrtf(rdx*rdx+rdy*rdy+rdz*rdz);

  // t bins
  if (coarse){
    if (tid <= 128) sh_t[tid] = 2.f + 4.f*(float)tid/128.f;
  } else {
    if (tid <= 128) sh_t[tid] = tfine_in[(size_t)ray*129 + tid];
  }
  // direnc (27 values)
  if (tid < 27){
    float v0=rdx/rn, v1=rdy/rn, v2=rdz/rn;
    float vv[3] = {v0,v1,v2};
    float o;
    if (tid < 3) o = vv[tid];
    else if (tid < 15){ int f=(tid-3)/3, j=(tid-3)%3; o = sinf(vv[j]*(float)(1<<f)); }
    else            { int f=(tid-15)/3, j=(tid-15)%3; o = cosf(vv[j]*(float)(1<<f)); }
    sh_de[tid] = o;
  }
  __syncthreads();

  // enc: sample s = tid>>2, part p = tid&3 handles freqs p*4..p*4+3 (all 3 axes)
  {
    int s = tid >> 2, p = tid & 3;
    float t0 = sh_t[s], t1 = sh_t[s+1];
    float c = 0.5f*(t0+t1), d = 0.5f*(t1-t0);
    float c2 = c*c, d2 = d*d;
    float denom = 3.f*c2 + d2;
    float t_mean = c + 2.f*c*d2/denom;
    float d4 = d2*d2;
    float t_var = d2*(1.f/3.f) - (4.f/15.f)*(d4*(12.f*c2 - d2))/(denom*denom);
    float rrv = rr[ray];
    float r_var = rrv*rrv*(c2*0.25f + (5.f/12.f)*d2 - (4.f/15.f)*d4/denom);
    float rdv[3] = {rdx, rdy, rdz};
    float rov[3] = {ro[ray*3], ro[ray*3+1], ro[ray*3+2]};
    float dd = rdx*rdx+rdy*rdy+rdz*rdz;
    float invdd = 1.f/fmaxf(dd, 1e-10f);
    #pragma unroll
    for (int j=0;j<3;j++){
      float mean = rov[j] + rdv[j]*t_mean;
      float doj = rdv[j]*rdv[j];
      float cov = t_var*doj + r_var*(1.f - doj*invdd);
      #pragma unroll
      for (int kk=p*4; kk<p*4+4; kk++){
        float sc = (float)(1<<kk);
        float att = expf(-0.5f*cov*sc*sc);
        float sv, cv;
        sincosf(mean*sc, &sv, &cv);
        float a0 = sv*att, a1 = cv*att;
        f16 h0=(f16)a0, h1=(f16)a1;
        int i0 = s*LP + kk*3 + j, i1 = s*LP + 48 + kk*3 + j;
        Xh[i0]=h0; Xl[i0]=(f16)(a0-(float)h0);
        Xh[i1]=h1; Xl[i1]=(f16)(a1-(float)h1);
      }
    }
    #pragma unroll
    for (int i=0;i<8;i++){
      int col = 96 + p*8 + i;
      Xh[s*LP+col]=(f16)0.f; Xl[s*LP+col]=(f16)0.f;
    }
  }
  __syncthreads();

  // dctr[j] = bd[j] + direnc . Wd[256:283, j]  (fp32; overlaps L0 k-loop on other waves)
  if (tid < 128){
    float acc = w.bd[tid];
    #pragma unroll
    for (int k=0;k<27;k++) acc = fmaf(sh_de[k], w.Wdfull[(size_t)(256+k)*128 + tid], acc);
    sh_dctr[tid] = acc;
  }

  // ---- MLP trunk ----
  mlp_layer<128,2>(Xh,Xl, w.W0h, w.W0l, w.b0, nullptr, 1, wave,q,r);
  mlp_layer<256,2>(Xh,Xl, w.Whh,          w.Whl,          w.bh,      nullptr, 1, wave,q,r);
  mlp_layer<256,2>(Xh,Xl, w.Whh+65536,    w.Whl+65536,    w.bh+256,  nullptr, 1, wave,q,r);
  mlp_layer<256,2>(Xh,Xl, w.Whh+131072,   w.Whl+131072,   w.bh+512,  nullptr, 1, wave,q,r);

  // sigma head (+ mus/sigs when coarse): 4 lanes per row, f16x8 vector LDS reads
  {
    int row = tid>>2, p = tid&3;
    const f16* xh = &Xh[row*LP + p*64];
    const f16* xl = &Xl[row*LP + p*64];
    float s0=0.f, s1=0.f, s2=0.f;
    #pragma unroll
    for (int i=0;i<8;i++){
      f16x8 vh = *(const f16x8*)(xh + i*8);
      f16x8 vl = *(const f16x8*)(xl + i*8);
      #pragma unroll
      for (int e=0;e<8;e++){
        int k = p*64 + i*8 + e;
        float xv = (float)vh[e] + (float)vl[e];
        s0 = fmaf(xv, w.Ws[k], s0);
        if (coarse){ s1 = fmaf(xv, w.Wm[2*k], s1); s2 = fmaf(xv, w.Wm[2*k+1], s2); }
      }
    }
    s0 += __shfl_xor(s0,1); s0 += __shfl_xor(s0,2);
    if (coarse){
      s1 += __shfl_xor(s1,1); s1 += __shfl_xor(s1,2);
      s2 += __shfl_xor(s2,1); s2 += __shfl_xor(s2,2);
    }
    if (p==0){
      sh_sig[row] = s0 + w.bs[0];
      if (coarse){
        sh_mu[row]  = sigmoidf(s1 + w.bm[0]);
        sh_sgm[row] = 2.f*(sigmoidf(s2 + w.bm[1]) + 0.001f);
      }
    }
  }
  // no barrier needed here: sh_sig/mu/sgm consumed only after later barriers

  // bottleneck (no relu) then Wd layer (adds dctr, relu, writes cols 0..127)
  mlp_layer<256,2>(Xh,Xl, w.Wbh, w.Wbl, w.bb, nullptr, 0, wave,q,r);
  mlp_layer<256,1>(Xh,Xl, w.Wdh, w.Wdl, nullptr, sh_dctr, 1, wave,q,r);

  // rgb head from h = X[:,0:128]: 4 lanes per row, 32 elems each
  {
    int row = tid>>2, p = tid&3;
    const f16* xh = &Xh[row*LP + p*32];
    const f16* xl = &Xl[row*LP + p*32];
    float s0=0.f,s1=0.f,s2=0.f;
    #pragma unroll
    for (int i=0;i<4;i++){
      f16x8 vh = *(const f16x8*)(xh + i*8);
      f16x8 vl = *(const f16x8*)(xl + i*8);
      #pragma unroll
      for (int e=0;e<8;e++){
        int k = p*32 + i*8 + e;
        float hv = (float)vh[e] + (float)vl[e];
        s0 = fmaf(hv, w.Wr[3*k  ], s0);
        s1 = fmaf(hv, w.Wr[3*k+1], s1);
        s2 = fmaf(hv, w.Wr[3*k+2], s2);
      }
    }
    s0 += __shfl_xor(s0,1); s0 += __shfl_xor(s0,2);
    s1 += __shfl_xor(s1,1); s1 += __shfl_xor(s1,2);
    s2 += __shfl_xor(s2,1); s2 += __shfl_xor(s2,2);
    if (p==0){
      sh_rgb[row*3  ] = s0 + w.br[0];
      sh_rgb[row*3+1] = s1 + w.br[1];
      sh_rgb[row*3+2] = s2 + w.br[2];
    }
  }
  __syncthreads();

  // ---- volume render (parallel scans + shuffle reductions) ----
  // alpha in register for tid<128
  float alpha = 0.f;
  if (tid < 128){
    float sg = fmaxf(sh_sig[tid], 0.f);
    float dist = coarse ? (0.03125f*rn) : ((sh_t[tid+1]-sh_t[tid])*rn);
    alpha = 1.f - expf(-sg*dist);
    if (coarse){
      float mu = sh_mu[tid], sm = sh_sgm[tid];
      float lt = approx_cdf_f((0.f-mu)/sm);
      sh_lt[tid] = lt;
      sh_pib[tid] = approx_cdf_f((1.f-mu)/sm) - lt;
    }
  }
  // exclusive product scan of (1-alpha+1e-10) over 128 (2 waves)
  float incl = 1.f;
  if (tid < 128){
    incl = 1.f - alpha + 1e-10f;
    #pragma unroll
    for (int off=1; off<64; off<<=1){
      float y = __shfl_up(incl, off);
      if (lane >= off) incl *= y;
    }
    if (lane == 63) red[8 + (tid>>6)] = incl;
  }
  __syncthreads();
  if (tid < 128){
    float basep = (tid >= 64) ? red[8] : 1.f;
    float prev = __shfl_up(incl, 1);
    float excl = (lane == 0) ? 1.f : prev;
    sh_w[tid] = alpha * excl * basep;
  }
  __syncthreads();

  // fused reductions
  {
    float a0=0.f,a1=0.f,a2=0.f,a3=0.f,a4=0.f;
    if (tid < 128){
      float wv = sh_w[tid];
      a0 = wv*sigmoidf(sh_rgb[tid*3+0]);
      a1 = wv*sigmoidf(sh_rgb[tid*3+1]);
      a2 = wv*sigmoidf(sh_rgb[tid*3+2]);
      if (coarse) a3 = wv + 1e-5f;
      else { a3 = wv*0.5f*(sh_t[tid]+sh_t[tid+1]); a4 = wv; }
      #pragma unroll
      for (int off=32; off>0; off>>=1){
        a0 += __shfl_down(a0,off); a1 += __shfl_down(a1,off);
        a2 += __shfl_down(a2,off); a3 += __shfl_down(a3,off);
        a4 += __shfl_down(a4,off);
      }
      if (lane == 0){
        int wv2 = tid>>6;
        red[wv2*5+0]=a0; red[wv2*5+1]=a1; red[wv2*5+2]=a2; red[wv2*5+3]=a3; red[wv2*5+4]=a4;
      }
    }
    __syncthreads();
    if (coarse){
      if (tid==0){
        dout[ray*3  ] = red[0]+red[5];
        dout[ray*3+1] = red[1]+red[6];
        dout[ray*3+2] = red[2]+red[7];
        s_wsum = red[3]+red[8];
      }
    } else {
      if (tid==0){
        dout[NRAYS*3 + ray*3  ] = red[0]+red[5];
        dout[NRAYS*3 + ray*3+1] = red[1]+red[6];
        dout[NRAYS*3 + ray*3+2] = red[2]+red[7];
        dout[NRAYS*6 + ray] = red[3]+red[8];
        dout[NRAYS*7 + ray] = red[4]+red[9];
      }
    }
  }
  if (!coarse) return;
  __syncthreads();

  // pdf + additive scan -> cdf
  float aincl = 0.f;
  if (tid < 128){
    sh_pdf[tid] = (sh_w[tid]+1e-5f)/s_wsum;
    aincl = sh_pdf[tid];
    #pragma unroll
    for (int off=1; off<64; off<<=1){
      float y = __shfl_up(aincl, off);
      if (lane >= off) aincl += y;
    }
    if (lane == 63) red[12 + (tid>>6)] = aincl;
  }
  __syncthreads();
  if (tid < 128){
    float addp = (tid >= 64) ? red[12] : 0.f;
    sh_cdf[tid+1] = aincl + addp;
    if (tid == 0) sh_cdf[0] = 0.f;
  }
  __syncthreads();

  if (tid < 129){
    float u = (float)tid * ((1.f-1e-5f)/128.f);
    int lo=0, hi=129;
    while (lo<hi){ int mid=(lo+hi)>>1; if (sh_cdf[mid] <= u) lo=mid+1; else hi=mid; }
    int idx = lo-1; idx = idx<0?0:(idx>127?127:idx);
    float frac = (u - sh_cdf[idx]) / fmaxf(sh_pdf[idx], 1e-10f);
    frac = fminf(fmaxf(frac,0.f),1.f);
    float p = sh_lt[idx] + frac*sh_pib[idx];
    p = fminf(fmaxf(p, 1e-5f), 1.f-1e-5f);
    float xx = sh_mu[idx] + sh_sgm[idx]*1.4142135623730951f*erfinvf_dev(2.f*p-1.f);
    xx = fminf(fmaxf(xx,0.f),1.f);
    float b0 = 2.f + 0.03125f*(float)idx;
    tfine_out[(size_t)ray*129+tid] = b0 + xx*0.03125f;
  }
}

extern "C" void kernel_launch(void* const* d_in, const int* in_sizes, int n_in,
                              void* d_out, int out_size, void* d_ws, size_t ws_size,
                              hipStream_t stream) {
  const float* ro  = (const float*)d_in[0];
  const float* rd  = (const float*)d_in[1];
  const float* rr  = (const float*)d_in[2];
  const float* cW0 = (const float*)d_in[3];  const float* cb0 = (const float*)d_in[4];
  const float* cWh = (const float*)d_in[5];  const float* cbh = (const float*)d_in[6];
  const float* cWs = (const float*)d_in[7];  const float* cbs = (const float*)d_in[8];
  const float* cWb = (const float*)d_in[9];  const float* cbb = (const float*)d_in[10];
  const float* cWd = (const float*)d_in[11]; const float* cbd = (const float*)d_in[12];
  const float* cWr = (const float*)d_in[13]; const float* cbr = (const float*)d_in[14];
  int iWm = 27, ibm = 28, ifb = 15;
  if (n_in > 15 && in_sizes[15] == 512){ iWm = 15; ibm = 16; ifb = 17; }
  const float* fW0 = (const float*)d_in[ifb+0];  const float* fb0 = (const float*)d_in[ifb+1];
  const float* fWh = (const float*)d_in[ifb+2];  const float* fbh = (const float*)d_in[ifb+3];
  const float* fWs = (const float*)d_in[ifb+4];  const float* fbs = (const float*)d_in[ifb+5];
  const float* fWb = (const float*)d_in[ifb+6];  const float* fbb = (const float*)d_in[ifb+7];
  const float* fWd = (const float*)d_in[ifb+8];  const float* fbd = (const float*)d_in[ifb+9];
  const float* fWr = (const float*)d_in[ifb+10]; const float* fbr = (const float*)d_in[ifb+11];
  const float* cWm = (const float*)d_in[iWm];    const float* cbm = (const float*)d_in[ibm];

  char* base = (char*)d_ws;
  size_t off = 0;
  auto alloc = [&](size_t bytes)->void*{ off = (off+63) & ~(size_t)63; void* p = base+off; off += bytes; return p; };

  float* tfine = (float*)alloc((size_t)NRAYS*129*4);
  f16 *cW0h=(f16*)alloc((size_t)256*128*2), *cW0l=(f16*)alloc((size_t)256*128*2);
  f16 *cWhh=(f16*)alloc((size_t)3*256*256*2), *cWhl=(f16*)alloc((size_t)3*256*256*2);
  f16 *cWbh=(f16*)alloc((size_t)256*256*2), *cWbl=(f16*)alloc((size_t)256*256*2);
  f16 *cWdh=(f16*)alloc((size_t)128*256*2), *cWdl=(f16*)alloc((size_t)128*256*2);
  f16 *fW0h=(f16*)alloc((size_t)256*128*2), *fW0l=(f16*)alloc((size_t)256*128*2);
  f16 *fWhh=(f16*)alloc((size_t)3*256*256*2), *fWhl=(f16*)alloc((size_t)3*256*256*2);
  f16 *fWbh=(f16*)alloc((size_t)256*256*2), *fWbl=(f16*)alloc((size_t)256*256*2);
  f16 *fWdh=(f16*)alloc((size_t)128*256*2), *fWdl=(f16*)alloc((size_t)128*256*2);

  // weight conversion+split (tiny)
  k_cvtT<<<(256*128+255)/256,256,0,stream>>>(cW0, cW0h, cW0l, 96, 256, 128);
  for (int i=0;i<3;i++)
    k_cvtT<<<(256*256+255)/256,256,0,stream>>>(cWh+(size_t)i*65536, cWhh+(size_t)i*65536, cWhl+(size_t)i*65536, 256, 256, 256);
  k_cvtT<<<(256*256+255)/256,256,0,stream>>>(cWb, cWbh, cWbl, 256, 256, 256);
  k_cvtT<<<(128*256+255)/256,256,0,stream>>>(cWd, cWdh, cWdl, 256, 128, 256);
  k_cvtT<<<(256*128+255)/256,256,0,stream>>>(fW0, fW0h, fW0l, 96, 256, 128);
  for (int i=0;i<3;i++)
    k_cvtT<<<(256*256+255)/256,256,0,stream>>>(fWh+(size_t)i*65536, fWhh+(size_t)i*65536, fWhl+(size_t)i*65536, 256, 256, 256);
  k_cvtT<<<(256*256+255)/256,256,0,stream>>>(fWb, fWbh, fWbl, 256, 256, 256);
  k_cvtT<<<(128*256+255)/256,256,0,stream>>>(fWd, fWdh, fWdl, 256, 128, 256);

  Weights wc = { cW0h,cW0l,cb0, cWhh,cWhl,cbh, cWs,cbs,cWm,cbm,
                 cWbh,cWbl,cbb, cWdh,cWdl,cWd,cbd, cWr,cbr };
  Weights wf = { fW0h,fW0l,fb0, fWhh,fWhl,fbh, fWs,fbs,nullptr,nullptr,
                 fWbh,fWbl,fbb, fWdh,fWdl,fWd,fbd, fWr,fbr };

  k_fused<<<NRAYS,512,0,stream>>>(ro, rd, rr, wc, nullptr, tfine, (float*)d_out, 1);
  k_fused<<<NRAYS,512,0,stream>>>(ro, rd, rr, wf, tfine, nullptr, (float*)d_out, 0);
}